// Round 22
// baseline (1169.435 us; speedup 1.0000x reference)
//
#include <hip/hip_runtime.h>

static constexpr int Mn  = 50000;
static constexpr int Nn  = 20000;
static constexpr int En  = 200000;
static constexpr int ESn = 100000;

typedef short short8v __attribute__((ext_vector_type(8)));
typedef short short4v __attribute__((ext_vector_type(4)));
typedef float f32x4   __attribute__((ext_vector_type(4)));

__device__ __forceinline__ float b2f(unsigned short h) {
  unsigned int u = ((unsigned int)h) << 16;
  return __builtin_bit_cast(float, u);
}
__device__ __forceinline__ unsigned short f2b(float f) {
  unsigned int u = __builtin_bit_cast(unsigned int, f);
  u = (u + 0x7FFFu + ((u >> 16) & 1u)) >> 16;
  return (unsigned short)u;
}
__device__ __forceinline__ void gld16(const void* g, void* l) {
  __builtin_amdgcn_global_load_lds(
      (const __attribute__((address_space(1))) void*)g,
      (__attribute__((address_space(3))) void*)l, 16, 0, 0);
}

// ---------------------------------------------------------------- fp32 -> bf16 flat convert
__global__ __launch_bounds__(256) void cvt_b(const float* __restrict__ s,
                                             unsigned short* __restrict__ d, long n) {
  long g  = (long)blockIdx.x*256 + threadIdx.x;
  long st = (long)gridDim.x*256;
  for (; g*8 < n; g += st) {
    const float4 a = *(const float4*)(s + g*8);
    const float4 b = *(const float4*)(s + g*8 + 4);
    short8v o;
    o[0]=(short)f2b(a.x); o[1]=(short)f2b(a.y); o[2]=(short)f2b(a.z); o[3]=(short)f2b(a.w);
    o[4]=(short)f2b(b.x); o[5]=(short)f2b(b.y); o[6]=(short)f2b(b.z); o[7]=(short)f2b(b.w);
    *(short8v*)(d + g*8) = o;
  }
}

// ---------------------------------------------------------------- W [K][N] fp32 -> packed MFMA-fragment order
__global__ __launch_bounds__(128) void wp_build(const float* __restrict__ W, int K, int N,
    unsigned short* __restrict__ WP, int KKd, int kg0) {
  const int t = threadIdx.x;
  const int kk2 = t >> 6, l = t & 63;
  const int c16 = blockIdx.x, ky = blockIdx.y;
  const int k0 = ky*64 + kk2*32 + (l>>4)*8;
  const int n  = c16*16 + (l&15);
  short8v o;
#pragma unroll
  for (int e=0;e<8;++e) o[e] = (short)f2b(W[(long)(k0+e)*N + n]);
  *(short8v*)(WP + (((long)c16*KKd + kg0 + ky*2+kk2)*64 + l)*8) = o;
}

// ---------------------------------------------------------------- KVW[a][c] = sum_b KV[a][b]*Wm[b][c]
__global__ __launch_bounds__(256) void kvw_mul(const float* __restrict__ KV,
    const float* __restrict__ Wm, float* __restrict__ KVW) {
  const int a = blockIdx.x;
  const int c = threadIdx.x;
  float s = 0.f;
  for (int b = 0; b < 256; ++b) s += KV[a*256 + b] * Wm[(long)b*256 + c];
  KVW[a*256 + c] = s;
}

// ---------------------------------------------------------------- index counting (deterministic int atomics)
__global__ __launch_bounds__(256) void count_idx(const int* __restrict__ idx, int n,
                                                 int* __restrict__ cnt) {
  int i = blockIdx.x*256 + threadIdx.x;
  const int st = gridDim.x*256;
  for (; i < n; i += st) atomicAdd(&cnt[idx[i]], 1);
}

// ---------------------------------------------------------------- fused K/V projection -> TRANSPOSED outputs
__global__ __launch_bounds__(256,3) void gemm_kv(
    const unsigned short* __restrict__ X, int aoff,
    const unsigned short* __restrict__ WkP, const unsigned short* __restrict__ WvP,
    unsigned short* __restrict__ KbT, unsigned short* __restrict__ VbT,
    float* __restrict__ pS, int ldp, int nrows, const int* __restrict__ cntw)
{
  __shared__ short xb[4][64*64];
  const int t = threadIdx.x;
  const int w = t >> 6, l = t & 63, q = l >> 4, hw = l & 15;
  const int r0 = blockIdx.x << 6;

  {
    const int sr = l >> 3, sc = l & 7;
    const int gcol = ((sc ^ sr) << 3);
#pragma unroll
    for (int j=0;j<2;++j) {
      int lr = r0 + j*32 + w*8 + sr;
      int lrc = lr < nrows ? lr : nrows-1;
      const unsigned short* src = X + (long)(aoff+lrc)*256 + gcol;
#pragma unroll
      for (int ks=0;ks<4;++ks)
        gld16(src + ks*64, &xb[ks][(j*32 + w*8)*64]);
    }
  }
  asm volatile("s_waitcnt vmcnt(0)" ::: "memory");
  __builtin_amdgcn_s_barrier();

#pragma unroll
  for (int pass=0; pass<2; ++pass) {
    const unsigned short* WP = pass ? WvP : WkP;
    unsigned short* O = pass ? VbT : KbT;
    f32x4 acc[4][4];
#pragma unroll
    for (int m=0;m<4;++m)
#pragma unroll
      for (int n=0;n<4;++n) acc[m][n] = (f32x4){0.f,0.f,0.f,0.f};
    short8v bfc[4], bfn[4];
#pragma unroll
    for (int n=0;n<4;++n)
      bfc[n] = *(const short8v*)(WP + (((long)(w*4+n)*8)*64 + l)*8);
#pragma unroll
    for (int st=0; st<8; ++st) {
      if (st < 7) {
#pragma unroll
        for (int n=0;n<4;++n)
          bfn[n] = *(const short8v*)(WP + (((long)(w*4+n)*8 + st+1)*64 + l)*8);
      }
      const int ks = st >> 1;
      const int kc = ((st&1)<<2) + q;
      short8v af[4];
#pragma unroll
      for (int m=0;m<4;++m)
        af[m] = *(const short8v*)&xb[ks][(m*16+hw)*64 + ((kc^(hw&7))<<3)];
      __builtin_amdgcn_s_setprio(1);
#pragma unroll
      for (int m=0;m<4;++m)
#pragma unroll
        for (int n=0;n<4;++n)
          acc[m][n] = __builtin_amdgcn_mfma_f32_16x16x32_bf16(af[m], bfc[n], acc[m][n], 0,0,0);
      __builtin_amdgcn_s_setprio(0);
#pragma unroll
      for (int n=0;n<4;++n) bfc[n] = bfn[n];
    }
    float colsum[4] = {0.f,0.f,0.f,0.f};
#pragma unroll
    for (int m=0;m<4;++m)
#pragma unroll
      for (int n=0;n<4;++n) {
        const int c = w*64 + n*16 + hw;
        short4v o4;
#pragma unroll
        for (int i=0;i<4;++i) {
          const int lr = r0 + m*16 + q*4 + i;
          float v = 0.f;
          if (lr < nrows) {
            v = acc[m][n][i];
            if (pass == 0) {
              v = v > 0.f ? v + 1.f : __expf(v);
              if (cntw) v *= (float)cntw[aoff + lr];
            }
          }
          if (pass == 0) colsum[n] += v;
          o4[i] = (short)f2b(v);
        }
        *(short4v*)(O + (long)c*ldp + r0 + m*16 + q*4) = o4;
      }
    if (pass == 0) {
#pragma unroll
      for (int n=0;n<4;++n) {
        float s = colsum[n];
        s += __shfl_xor(s, 16);
        s += __shfl_xor(s, 32);
        if (q == 0) pS[(long)blockIdx.x*256 + w*64 + n*16 + hw] = s;
      }
    }
  }
}

// Ks[c] += sum_b pS[b][c]  (one block per column)
__global__ __launch_bounds__(256) void ksum_red(const float* __restrict__ pS, int nb,
    float* __restrict__ Ks) {
  __shared__ float ws[4];
  const int c = blockIdx.x;
  const int t = threadIdx.x;
  float s = 0.f;
  for (int b = t; b < nb; b += 256) s += pS[(long)b*256 + c];
#pragma unroll
  for (int off=32; off; off>>=1) s += __shfl_xor(s, off);
  if ((t & 63) == 0) ws[t >> 6] = s;
  __syncthreads();
  if (t == 0) Ks[c] += ws[0] + ws[1] + ws[2] + ws[3];
}

// ---------------------------------------------------------------- K^T V via MFMA, LDS-free streaming
__global__ __launch_bounds__(256,4) void ktv_mfma(
    const unsigned short* __restrict__ KbT, const unsigned short* __restrict__ VbT,
    int ldp, int rpp, float* __restrict__ pKV)
{
  const int t  = threadIdx.x;
  const int w  = t >> 6;
  const int l  = t & 63;
  const int q  = l >> 4;
  const int hw = l & 15;
  const int wa = w >> 1, wb = w & 1;
  const int a0 = blockIdx.x << 7;
  const int b0 = blockIdx.y << 7;
  const int rbeg = blockIdx.z * rpp;
  const int rend = min(ldp, rbeg + rpp);

  f32x4 acc[4][4];
#pragma unroll
  for (int m=0;m<4;++m)
#pragma unroll
    for (int n=0;n<4;++n) acc[m][n] = (f32x4){0.f,0.f,0.f,0.f};

  const unsigned short* ap[4];
  const unsigned short* bp[4];
#pragma unroll
  for (int m=0;m<4;++m) ap[m] = KbT + (long)(a0 + wa*64 + m*16 + hw)*ldp + q*8;
#pragma unroll
  for (int n=0;n<4;++n) bp[n] = VbT + (long)(b0 + wb*64 + n*16 + hw)*ldp + q*8;

#pragma unroll 4
  for (int r = rbeg; r < rend; r += 32) {
    short8v af[4], bf[4];
#pragma unroll
    for (int m=0;m<4;++m) af[m] = *(const short8v*)(ap[m] + r);
#pragma unroll
    for (int n=0;n<4;++n) bf[n] = *(const short8v*)(bp[n] + r);
#pragma unroll
    for (int m=0;m<4;++m)
#pragma unroll
      for (int n=0;n<4;++n)
        acc[m][n] = __builtin_amdgcn_mfma_f32_16x16x32_bf16(af[m], bf[n], acc[m][n], 0,0,0);
  }

  const long base = (long)blockIdx.z * 65536;
#pragma unroll
  for (int m=0;m<4;++m)
#pragma unroll
    for (int i=0;i<4;++i) {
      const int a = a0 + wa*64 + m*16 + q*4 + i;
#pragma unroll
      for (int n=0;n<4;++n) {
        const int b = b0 + wb*64 + n*16 + hw;
        pKV[base + (long)a*256 + b] = acc[m][n][i];
      }
    }
}

__global__ __launch_bounds__(256) void kv_accum(const float* __restrict__ pKV, int P,
                                                float* __restrict__ KV) {
  const int i = blockIdx.x*256 + threadIdx.x;
  float s = 0.f;
  for (int p=0;p<P;++p) s += pKV[(long)p*65536 + i];
  KV[i] += s;
}

// ---------------------------------------------------------------- fused encoder phase B, 64 rows/block
// 8-wave (512-thread) variant: wc = w&3 column group, wr = w>>2 row half (rows wr*32..wr*32+31).
// OMODE: 0 = bf16 out; 1 = f32 out; 2 = bf16 kept in LDS + EW4 = out@W4 (f32) tail
template<int OMODE>
__global__ __launch_bounds__(512,4) void encB(
    const unsigned short* __restrict__ X, int aoff,
    const unsigned short* __restrict__ WqP, const unsigned short* __restrict__ KVWP,
    const unsigned short* __restrict__ m1P, const unsigned short* __restrict__ m2P,
    const float* __restrict__ Ksum, const float* __restrict__ bmv,
    const float* __restrict__ l1g, const float* __restrict__ l1b,
    const float* __restrict__ mb1, const float* __restrict__ mb2,
    const float* __restrict__ l2g, const float* __restrict__ l2b,
    const unsigned short* __restrict__ WfP,
    void* outv, int dc0, int nrows)
{
  __shared__ short xb[4][64*64];
  __shared__ short qb[4][64*64];
  __shared__ short y1b[64*64];
  __shared__ float2 red[64][4];
  __shared__ float Zl[64];

  const int t = threadIdx.x;
  const int w = t >> 6, l = t & 63, q = l >> 4, hw = l & 15;
  const int wc = w & 3, wr = w >> 2;
  const int rb = wr * 32;
  const int r0 = blockIdx.x << 6;
  const int sr = l >> 3, sc = l & 7;
  const int gcol = ((sc ^ sr) << 3);

  {
    int lr = r0 + w*8 + sr;
    int lrc = lr < nrows ? lr : nrows-1;
    const unsigned short* src = X + (long)(aoff+lrc)*256 + gcol;
#pragma unroll
    for (int ks=0;ks<4;++ks)
      gld16(src + ks*64, &xb[ks][(w*8 + sr)*64]);
  }
  asm volatile("s_waitcnt vmcnt(0)" ::: "memory");
  __builtin_amdgcn_s_barrier();

  f32x4 acc[2][4];

  auto GEMM256 = [&](const short* Asrc, const unsigned short* WP) {
#pragma unroll
    for (int m=0;m<2;++m)
#pragma unroll
      for (int n=0;n<4;++n) acc[m][n] = (f32x4){0.f,0.f,0.f,0.f};
    short8v bfc[4], bfn[4];
#pragma unroll
    for (int n=0;n<4;++n)
      bfc[n] = *(const short8v*)(WP + (((long)(wc*4+n)*8)*64 + l)*8);
#pragma unroll
    for (int st=0; st<8; ++st) {
      if (st < 7) {
#pragma unroll
        for (int n=0;n<4;++n)
          bfn[n] = *(const short8v*)(WP + (((long)(wc*4+n)*8 + st+1)*64 + l)*8);
      }
      const int ks = st >> 1;
      const int kc = ((st&1)<<2) + q;
      short8v af[2];
#pragma unroll
      for (int m=0;m<2;++m)
        af[m] = *(const short8v*)&Asrc[ks*4096 + (rb + m*16+hw)*64 + ((kc^(hw&7))<<3)];
      __builtin_amdgcn_s_setprio(1);
#pragma unroll
      for (int m=0;m<2;++m)
#pragma unroll
        for (int n=0;n<4;++n)
          acc[m][n] = __builtin_amdgcn_mfma_f32_16x16x32_bf16(af[m], bfc[n], acc[m][n], 0,0,0);
      __builtin_amdgcn_s_setprio(0);
#pragma unroll
      for (int n=0;n<4;++n) bfc[n] = bfn[n];
    }
  };

  // G1: Q = elu1(x @ Wq), Z partials
  GEMM256(&xb[0][0], WqP);
  {
    float ksv[4];
#pragma unroll
    for (int n=0;n<4;++n) ksv[n] = Ksum[wc*64+n*16+hw];
#pragma unroll
    for (int m=0;m<2;++m)
#pragma unroll
      for (int n=0;n<4;++n)
#pragma unroll
        for (int i=0;i<4;++i) {
          float v = acc[m][n][i];
          acc[m][n][i] = v > 0.f ? v + 1.f : __expf(v);
        }
#pragma unroll
    for (int m=0;m<2;++m)
#pragma unroll
      for (int i=0;i<4;++i) {
        float z = 0.f;
#pragma unroll
        for (int n=0;n<4;++n) z += acc[m][n][i]*ksv[n];
#pragma unroll
        for (int off=1; off<16; off<<=1) z += __shfl_xor(z, off);
        if (hw==0) red[rb + m*16+q*4+i][wc] = make_float2(z, 0.f);
      }
#pragma unroll
    for (int m=0;m<2;++m)
#pragma unroll
      for (int i=0;i<4;++i) {
        const int row = rb + m*16+q*4+i;
        const int sw = row & 7;
#pragma unroll
        for (int n=0;n<4;++n)
          qb[wc][row*64 + (((n*2+(hw>>3)) ^ sw)<<3) + (hw&7)] = (short)f2b(acc[m][n][i]);
      }
  }
  __syncthreads();
  if (wc==0 && hw==0) {
#pragma unroll
    for (int m=0;m<2;++m)
#pragma unroll
      for (int i=0;i<4;++i) {
        const int row = rb + m*16+q*4+i;
        Zl[row] = red[row][0].x + red[row][1].x + red[row][2].x + red[row][3].x + 1e-6f;
      }
  }

  // G2': msg = LN((Q @ KVW)/Z + bm)
  GEMM256(&qb[0][0], KVWP);
  __syncthreads();
#pragma unroll
  for (int m=0;m<2;++m) {
    const f32x4 z = *(const f32x4*)&Zl[rb + m*16+q*4];
#pragma unroll
    for (int i=0;i<4;++i) {
      const float iz = 1.f / z[i];
#pragma unroll
      for (int n=0;n<4;++n) acc[m][n][i] *= iz;
    }
  }
  {
    float lg[4], lb[4];
#pragma unroll
    for (int n=0;n<4;++n) {
      const int c = wc*64+n*16+hw;
      const float bv = bmv[c];
      lg[n] = l1g[c]; lb[n] = l1b[c];
#pragma unroll
      for (int m=0;m<2;++m)
#pragma unroll
        for (int i=0;i<4;++i) acc[m][n][i] += bv;
    }
    float s1[2][4], s2[2][4];
#pragma unroll
    for (int m=0;m<2;++m)
#pragma unroll
      for (int i=0;i<4;++i) {
        float s=0.f, sq=0.f;
#pragma unroll
        for (int n=0;n<4;++n){ const float v=acc[m][n][i]; s+=v; sq+=v*v; }
        s1[m][i]=s; s2[m][i]=sq;
      }
#pragma unroll
    for (int off=1; off<16; off<<=1)
#pragma unroll
      for (int m=0;m<2;++m)
#pragma unroll
        for (int i=0;i<4;++i) {
          s1[m][i] += __shfl_xor(s1[m][i], off);
          s2[m][i] += __shfl_xor(s2[m][i], off);
        }
    if (hw==0) {
#pragma unroll
      for (int m=0;m<2;++m)
#pragma unroll
        for (int i=0;i<4;++i)
          red[rb + m*16+q*4+i][wc] = make_float2(s1[m][i], s2[m][i]);
    }
    __syncthreads();
#pragma unroll
    for (int m=0;m<2;++m)
#pragma unroll
      for (int i=0;i<4;++i) {
        const int row = rb + m*16+q*4+i;
        float ts=0.f, tq=0.f;
#pragma unroll
        for (int ww=0;ww<4;++ww){ const float2 v=red[row][ww]; ts+=v.x; tq+=v.y; }
        const float mmu = ts*(1.f/256.f);
        float var = tq*(1.f/256.f) - mmu*mmu;
        var = var>0.f ? var : 0.f;
        const float rs = rsqrtf(var + 1e-5f);
        const int sw = row & 7;
#pragma unroll
        for (int n=0;n<4;++n) {
          const float v = (acc[m][n][i]-mmu)*rs*lg[n] + lb[n];
          qb[wc][row*64 + (((n*2+(hw>>3)) ^ sw)<<3) + (hw&7)] = (short)f2b(v);
        }
      }
  }
  __syncthreads();

  // MLP
  f32x4 oacc[2][4];
#pragma unroll
  for (int m=0;m<2;++m)
#pragma unroll
    for (int n=0;n<4;++n) oacc[m][n] = (f32x4){0.f,0.f,0.f,0.f};

  for (int ct=0; ct<8; ++ct) {
    f32x4 ya[2];
#pragma unroll
    for (int m=0;m<2;++m) ya[m] = (f32x4){0.f,0.f,0.f,0.f};
    {
      short8v b0c, b0n;
      b0c = *(const short8v*)(m1P + (((long)(ct*4+wc)*16)*64 + l)*8);
#pragma unroll
      for (int st=0; st<16; ++st) {
        if (st < 15)
          b0n = *(const short8v*)(m1P + (((long)(ct*4+wc)*16 + st+1)*64 + l)*8);
        const int ks = st >> 1;
        const int kc = ((st&1)<<2) + q;
        const short* As_ = (ks<4) ? &xb[ks][0] : &qb[ks-4][0];
        __builtin_amdgcn_s_setprio(1);
#pragma unroll
        for (int m=0;m<2;++m) {
          const short8v af = *(const short8v*)&As_[(rb + m*16+hw)*64 + ((kc^(hw&7))<<3)];
          ya[m] = __builtin_amdgcn_mfma_f32_16x16x32_bf16(af, b0c, ya[m], 0,0,0);
        }
        __builtin_amdgcn_s_setprio(0);
        b0c = b0n;
      }
    }
    const float b1 = mb1[ct*64 + wc*16 + hw];
#pragma unroll
    for (int m=0;m<2;++m)
#pragma unroll
      for (int i=0;i<4;++i) {
        const int row = rb + m*16+q*4+i;
        float v = ya[m][i] + b1; v = v>0.f ? v : 0.f;
        y1b[row*64 + (((wc*2+(hw>>3)) ^ (row&7))<<3) + (hw&7)] = (short)f2b(v);
      }
    __syncthreads();
    {
      short8v bfc[4], bfn[4];
#pragma unroll
      for (int n=0;n<4;++n)
        bfc[n] = *(const short8v*)(m2P + (((long)(wc*4+n)*16 + ct*2)*64 + l)*8);
#pragma unroll
      for (int kk=0;kk<2;++kk) {
        if (kk == 0) {
#pragma unroll
          for (int n=0;n<4;++n)
            bfn[n] = *(const short8v*)(m2P + (((long)(wc*4+n)*16 + ct*2+1)*64 + l)*8);
        }
        const int kc = (kk<<2)+q;
        short8v af[2];
#pragma unroll
        for (int m=0;m<2;++m)
          af[m] = *(const short8v*)&y1b[(rb + m*16+hw)*64 + ((kc^(hw&7))<<3)];
        __builtin_amdgcn_s_setprio(1);
#pragma unroll
        for (int m=0;m<2;++m)
#pragma unroll
          for (int n=0;n<4;++n)
            oacc[m][n] = __builtin_amdgcn_mfma_f32_16x16x32_bf16(af[m], bfc[n], oacc[m][n], 0,0,0);
        __builtin_amdgcn_s_setprio(0);
#pragma unroll
        for (int n=0;n<4;++n) bfc[n] = bfn[n];
      }
    }
    __syncthreads();
  }

  // final: out = x + LN(oacc + mb2)
  {
    float lg[4], lb[4];
#pragma unroll
    for (int n=0;n<4;++n) {
      const int c = wc*64+n*16+hw;
      const float bv = mb2[c];
      lg[n] = l2g[c]; lb[n] = l2b[c];
#pragma unroll
      for (int m=0;m<2;++m)
#pragma unroll
        for (int i=0;i<4;++i) oacc[m][n][i] += bv;
    }
    float s1[2][4], s2[2][4];
#pragma unroll
    for (int m=0;m<2;++m)
#pragma unroll
      for (int i=0;i<4;++i) {
        float s=0.f, sq=0.f;
#pragma unroll
        for (int n=0;n<4;++n){ const float v=oacc[m][n][i]; s+=v; sq+=v*v; }
        s1[m][i]=s; s2[m][i]=sq;
      }
#pragma unroll
    for (int off=1; off<16; off<<=1)
#pragma unroll
      for (int m=0;m<2;++m)
#pragma unroll
        for (int i=0;i<4;++i) {
          s1[m][i] += __shfl_xor(s1[m][i], off);
          s2[m][i] += __shfl_xor(s2[m][i], off);
        }
    if (hw==0) {
#pragma unroll
      for (int m=0;m<2;++m)
#pragma unroll
        for (int i=0;i<4;++i)
          red[rb + m*16+q*4+i][wc] = make_float2(s1[m][i], s2[m][i]);
    }
    __syncthreads();
#pragma unroll
    for (int m=0;m<2;++m)
#pragma unroll
      for (int i=0;i<4;++i) {
        const int row = rb + m*16+q*4+i;
        const int lr = r0 + row;
        if (lr >= nrows) continue;
        float ts=0.f, tq=0.f;
#pragma unroll
        for (int ww=0;ww<4;++ww){ const float2 v=red[row][ww]; ts+=v.x; tq+=v.y; }
        const float mmu = ts*(1.f/256.f);
        float var = tq*(1.f/256.f) - mmu*mmu;
        var = var>0.f ? var : 0.f;
        const float rs = rsqrtf(var + 1e-5f);
        const int sw = row & 7;
#pragma unroll
        for (int n=0;n<4;++n) {
          const int c = wc*64+n*16+hw;
          float v = (oacc[m][n][i]-mmu)*rs*lg[n] + lb[n];
          v += b2f((unsigned short)xb[wc][row*64 + (((n*2+(hw>>3)) ^ sw)<<3) + (hw&7)]);
          if constexpr (OMODE == 2) {
            qb[wc][row*64 + (((n*2+(hw>>3)) ^ sw)<<3) + (hw&7)] = (short)f2b(v);
          } else {
            const long off2 = (long)(dc0+lr)*256 + c;
            if constexpr (OMODE == 1) ((float*)outv)[off2] = v;
            else ((unsigned short*)outv)[off2] = f2b(v);
          }
        }
      }
  }

  // fused tail (OMODE==2): EW4 = out @ W4 (f32)
  if constexpr (OMODE == 2) {
    __syncthreads();
    GEMM256(&qb[0][0], WfP);
#pragma unroll
    for (int m=0;m<2;++m)
#pragma unroll
      for (int i=0;i<4;++i) {
        const int lr = r0 + rb + m*16 + q*4 + i;
        if (lr >= nrows) continue;
#pragma unroll
        for (int n=0;n<4;++n)
          ((float*)outv)[(long)(dc0+lr)*256 + wc*64+n*16+hw] = acc[m][n][i];
      }
  }
}

// ---------------------------------------------------------------- fused conv + W2 + EW4 gather + BN partials
// r16 form (occ 3, f32 conv reads) + fused per-block BN sum/sumsq partials.
__global__ __launch_bounds__(256,3) void edge_final(
    const float* __restrict__ h, const int* __restrict__ gs, const int* __restrict__ gd,
    const float* __restrict__ cw, const float* __restrict__ cb,
    const unsigned short* __restrict__ W2P, const float* __restrict__ EW4,
    const float* __restrict__ b4, const float* __restrict__ b2,
    float* __restrict__ lr_e, float* __restrict__ pstat, int nrows)
{
  __shared__ short xb[4][64*64];
  const int t = threadIdx.x;
  const int w = t >> 6, l = t & 63, q = l >> 4, hw = l & 15;
  const int r0 = blockIdx.x << 6;

  const float c0=cw[0],c1=cw[1],c2=cw[2],c3=cw[3],c4=cw[4],c5=cw[5],cbb=cb[0];
  for (int it=0; it<16; ++it) {
    const int row = w*16 + it;
    const int lr = r0 + row;
    const int lrc = lr < nrows ? lr : nrows-1;
    const float4 s = *(const float4*)(h + (long)gs[lrc]*256 + l*4);
    const float4 d = *(const float4*)(h + (long)gd[lrc]*256 + l*4);
    float smw = __shfl_up(s.w, 1); if (l==0) smw = 0.f;
    float spx = __shfl_down(s.x, 1); if (l==63) spx = 0.f;
    float dmw = __shfl_up(d.w, 1); if (l==0) dmw = 0.f;
    float dpx = __shfl_down(d.x, 1); if (l==63) dpx = 0.f;
    short4v o;
    o[0]=(short)f2b(cbb + c0*smw + c1*s.x + c2*s.y + c3*dmw + c4*d.x + c5*d.y);
    o[1]=(short)f2b(cbb + c0*s.x + c1*s.y + c2*s.z + c3*d.x + c4*d.y + c5*d.z);
    o[2]=(short)f2b(cbb + c0*s.y + c1*s.z + c2*s.w + c3*d.y + c4*d.z + c5*d.w);
    o[3]=(short)f2b(cbb + c0*s.z + c1*s.w + c2*spx + c3*d.z + c4*d.w + c5*dpx);
    const int ks = l >> 4;
    const int g  = (l & 15) >> 1;
    *(short4v*)&xb[ks][row*64 + ((g ^ (row&7))<<3) + (l&1)*4] = o;
  }
  __syncthreads();

  f32x4 acc[4][4];
#pragma unroll
  for (int m=0;m<4;++m)
#pragma unroll
    for (int n=0;n<4;++n) acc[m][n] = (f32x4){0.f,0.f,0.f,0.f};
  short8v bfc[4], bfn[4];
#pragma unroll
  for (int n=0;n<4;++n)
    bfc[n] = *(const short8v*)(W2P + (((long)(w*4+n)*8)*64 + l)*8);
#pragma unroll
  for (int st=0; st<8; ++st) {
    if (st < 7) {
#pragma unroll
      for (int n=0;n<4;++n)
        bfn[n] = *(const short8v*)(W2P + (((long)(w*4+n)*8 + st+1)*64 + l)*8);
    }
    const int ks = st >> 1;
    const int kc = ((st&1)<<2) + q;
    short8v af[4];
#pragma unroll
    for (int m=0;m<4;++m)
      af[m] = *(const short8v*)&xb[ks][(m*16+hw)*64 + ((kc^(hw&7))<<3)];
    __builtin_amdgcn_s_setprio(1);
#pragma unroll
    for (int m=0;m<4;++m)
#pragma unroll
      for (int n=0;n<4;++n)
        acc[m][n] = __builtin_amdgcn_mfma_f32_16x16x32_bf16(af[m], bfc[n], acc[m][n], 0,0,0);
    __builtin_amdgcn_s_setprio(0);
#pragma unroll
    for (int n=0;n<4;++n) bfc[n] = bfn[n];
  }
  float bia[4];
#pragma unroll
  for (int n=0;n<4;++n) {
    const int c = w*64+n*16+hw;
    bia[n] = b4[c] + b2[c];
  }
  float cs[4] = {0.f,0.f,0.f,0.f};
  float cq2[4] = {0.f,0.f,0.f,0.f};
#pragma unroll
  for (int m=0;m<4;++m)
#pragma unroll
    for (int i=0;i<4;++i) {
      const int lr = r0 + m*16 + q*4 + i;
      if (lr >= nrows) continue;
      const long rid = (long)gs[lr];
#pragma unroll
      for (int n=0;n<4;++n) {
        const int c = w*64+n*16+hw;
        const float v = acc[m][n][i] + EW4[rid*256 + c] + bia[n];
        cs[n] += v; cq2[n] += v*v;
        lr_e[(long)lr*256 + c] = v;
      }
    }
#pragma unroll
  for (int n=0;n<4;++n) {
    float a = cs[n];
    a += __shfl_xor(a, 16);
    a += __shfl_xor(a, 32);
    float b = cq2[n];
    b += __shfl_xor(b, 16);
    b += __shfl_xor(b, 32);
    if (q == 0) {
      const int c = w*64+n*16+hw;
      pstat[(long)blockIdx.x*512 + c] = a;
      pstat[(long)blockIdx.x*512 + 256 + c] = b;
    }
  }
}

// ---------------------------------------------------------------- BN apply (in place, f32)
template<bool R>
__global__ __launch_bounds__(256) void bn_apply(float* __restrict__ X, long rows,
    const float* __restrict__ sc, const float* __restrict__ sh) {
  const long n4 = rows*64;
  long i = (long)blockIdx.x*256 + threadIdx.x;
  const long st = (long)gridDim.x*256;
  for (; i<n4; i+=st) {
    const int cq = (int)(i & 63);
    float4 v = ((float4*)X)[i];
    const float4 s4 = ((const float4*)sc)[cq];
    const float4 h4 = ((const float4*)sh)[cq];
    v.x = v.x*s4.x + h4.x; v.y = v.y*s4.y + h4.y;
    v.z = v.z*s4.z + h4.z; v.w = v.w*s4.w + h4.w;
    if (R) { v.x=fmaxf(v.x,0.f); v.y=fmaxf(v.y,0.f); v.z=fmaxf(v.z,0.f); v.w=fmaxf(v.w,0.f); }
    ((float4*)X)[i] = v;
  }
}

// count-weighted node stats: part[b][512] over 64 blocks
__global__ __launch_bounds__(256) void bnw_stats(const float* __restrict__ X,
    const int* __restrict__ cnt, int rows, float* __restrict__ part) {
  const int b = blockIdx.x, c = threadIdx.x;
  float s=0.f, s2=0.f;
  for (int r=b; r<rows; r+=64) {
    const float wgt = (float)cnt[r];
    if (wgt != 0.f) {
      const float v = X[(long)r*256 + c];
      s += wgt*v; s2 += wgt*v*v;
    }
  }
  part[(long)b*512 + c] = s;
  part[(long)b*512 + 256 + c] = s2;
}

__global__ __launch_bounds__(256) void bn_mid(const float* __restrict__ part, int PE,
    float* __restrict__ mid) {
  const int g = blockIdx.x, c = threadIdx.x;
  float s=0.f, s2=0.f;
  for (int p=g; p<PE; p+=64) {
    s  += part[(long)p*512 + c];
    s2 += part[(long)p*512 + 256 + c];
  }
  mid[(long)g*512 + c] = s;
  mid[(long)g*512 + 256 + c] = s2;
}

__global__ __launch_bounds__(256) void bn_finalize(const float* __restrict__ part, int P,
    long rows, const float* __restrict__ g, const float* __restrict__ b,
    float* __restrict__ scale, float* __restrict__ shift) {
  const int c = threadIdx.x;
  float s=0.f, s2=0.f;
  for (int p=0;p<P;++p) { s += part[(long)p*512 + c]; s2 += part[(long)p*512 + 256 + c]; }
  const float inv = 1.f/(float)rows;
  const float mu = s*inv;
  float var = s2*inv - mu*mu;
  var = var > 0.f ? var : 0.f;
  const float rs = rsqrtf(var + 1e-5f);
  scale[c] = g[c]*rs;
  shift[c] = b[c] - mu*g[c]*rs;
}

// soc[e] = nodeS[s_src[e]]*scale + shift
__global__ __launch_bounds__(256) void bn_apply_gather(const float* __restrict__ nodeS,
    const int* __restrict__ sidx, long rows,
    const float* __restrict__ sc, const float* __restrict__ sh,
    float* __restrict__ out) {
  const long n4 = rows*64;
  long i = (long)blockIdx.x*256 + threadIdx.x;
  const long st = (long)gridDim.x*256;
  for (; i<n4; i+=st) {
    const long row = i >> 6;
    const int cq = (int)(i & 63);
    const long rid = (long)sidx[row];
    float4 v = *(const float4*)(nodeS + rid*256 + cq*4);
    const float4 s4 = ((const float4*)sc)[cq];
    const float4 h4 = ((const float4*)sh)[cq];
    v.x = v.x*s4.x + h4.x; v.y = v.y*s4.y + h4.y;
    v.z = v.z*s4.z + h4.z; v.w = v.w*s4.w + h4.w;
    ((float4*)out)[i] = v;
  }
}

// ---------------------------------------------------------------- host-side
struct Ctx {
  const unsigned short *WkP,*WvP,*WqP,*m1P,*m2P;
  unsigned short* KVWP;
  const float *Wm;
  float* KVW;
  const float *bm,*l1g,*l1b,*mb1,*mb2,*l2g,*l2b;
  unsigned short *bufA,*bufB;
  float *pKV,*pS,*KV;
  long CH;
  hipStream_t st;
};

static void phaseA(const Ctx& c, long S, const unsigned short* Bsrc, const int* cnt) {
  hipMemsetAsync(c.KV, 0, 65792*sizeof(float), c.st);
  for (long s0=0; s0<S; s0+=c.CH) {
    const int n = (int)((S-s0 < c.CH) ? (S-s0) : c.CH);
    const int gb = (n+63)/64;
    const int ldp = gb*64;
    gemm_kv<<<gb,256,0,c.st>>>(Bsrc, (int)s0, c.WkP, c.WvP, c.bufA, c.bufB, c.pS, ldp, n, cnt);
    const int P = (ldp+511)/512;
    ktv_mfma<<<dim3(2,2,P),256,0,c.st>>>(c.bufA, c.bufB, ldp, 512, c.pKV);
    kv_accum<<<256,256,0,c.st>>>(c.pKV, P, c.KV);
    ksum_red<<<256,256,0,c.st>>>(c.pS, gb, c.KV+65536);
  }
  kvw_mul<<<256,256,0,c.st>>>(c.KV, c.Wm, c.KVW);
  wp_build<<<dim3(16,4),128,0,c.st>>>(c.KVW, 256, 256, c.KVWP, 8, 0);
}

template<int OMODE>
static void phaseB(const Ctx& c, long L, const unsigned short* Asrc, void* out,
                   const unsigned short* WfP) {
  const float* Ksum = c.KV + 65536;
  for (long l0=0; l0<L; l0+=c.CH) {
    const int n = (int)((L-l0 < c.CH) ? (L-l0) : c.CH);
    const int gb = (n+63)/64;
    encB<OMODE><<<gb,512,0,c.st>>>(Asrc, (int)l0,
        c.WqP, c.KVWP, c.m1P, c.m2P, Ksum, c.bm, c.l1g, c.l1b,
        c.mb1, c.mb2, c.l2g, c.l2b, WfP, out, (int)l0, n);
  }
}

extern "C" void kernel_launch(void* const* d_in, const int* in_sizes, int n_in,
                              void* d_out, int out_size, void* d_ws, size_t ws_size,
                              hipStream_t stream) {
  const float* h_nodes = (const float*)d_in[0];
  const float* s_u     = (const float*)d_in[1];
  const int*   g_src   = (const int*)d_in[2];
  const int*   g_dst   = (const int*)d_in[3];
  const int*   s_src   = (const int*)d_in[4];
  const int*   s_dst   = (const int*)d_in[5];
  const float* conv_w  = (const float*)d_in[6];
  const float* conv_b  = (const float*)d_in[7];
  const float* W2      = (const float*)d_in[8];
  const float* b2      = (const float*)d_in[9];
  const float* W4      = (const float*)d_in[10];
  const float* b4      = (const float*)d_in[11];
  const float* bn_g    = (const float*)d_in[12];
  const float* bn_b    = (const float*)d_in[13];
  const float* Wq      = (const float*)d_in[14];
  const float* Wk      = (const float*)d_in[15];
  const float* Wv      = (const float*)d_in[16];
  const float* Wm      = (const float*)d_in[17];
  const float* bm      = (const float*)d_in[18];
  const float* l1g     = (const float*)d_in[19];
  const float* l1b     = (const float*)d_in[20];
  const float* mw1     = (const float*)d_in[21];
  const float* mb1     = (const float*)d_in[22];
  const float* mw2     = (const float*)d_in[23];
  const float* mb2     = (const float*)d_in[24];
  const float* l2g     = (const float*)d_in[25];
  const float* l2b     = (const float*)d_in[26];
  (void)in_sizes; (void)n_in; (void)out_size;

  float* lr_e = (float*)d_out;                 // [E,256]
  float* soc  = lr_e + (size_t)En*256;         // [ES,256]

  char* base = (char*)d_ws;
  size_t off = 0;
  auto carve = [&](size_t bytes)->void* {
    void* p = (void*)(base + off);
    off = (off + bytes + 255) & ~(size_t)255;
    return p;
  };
  unsigned short* h_nb = (unsigned short*)carve((size_t)Mn*256*2);
  unsigned short* s_ub = (unsigned short*)carve((size_t)Nn*256*2);
  unsigned short* WkP  = (unsigned short*)carve(65536*2);
  unsigned short* WvP  = (unsigned short*)carve(65536*2);
  unsigned short* WqP  = (unsigned short*)carve(65536*2);
  unsigned short* m1P  = (unsigned short*)carve(262144*2);
  unsigned short* m2P  = (unsigned short*)carve(131072*2);
  unsigned short* W4P  = (unsigned short*)carve(65536*2);
  unsigned short* W2P  = (unsigned short*)carve(65536*2);
  unsigned short* KVWP = (unsigned short*)carve(65536*2);
  float* KV            = (float*)carve(65792*4);
  float* KVW           = (float*)carve(65536*4);
  float* bnpart        = (float*)carve((size_t)3200*512*4);
  float* bnmid         = (float*)carve((size_t)64*512*4);
  float* bnscale       = (float*)carve(256*4);
  float* bnshift       = (float*)carve(256*4);
  float* EW4           = (float*)carve((size_t)Mn*256*4);
  float* nodeS         = (float*)carve((size_t)Nn*256*4);
  int* cntg            = (int*)carve((size_t)Mn*4);
  int* cnts            = (int*)carve((size_t)Nn*4);
  int* cntss           = (int*)carve((size_t)Nn*4);

  const size_t remain = ws_size > off ? ws_size - off : 0;
  // per 1024 rows: bufA+bufB 1 MiB + pKV 512 KiB + pS 16 KiB
  long CH = (long)(remain / 1589248) * 1024;
  if (CH > 65536) CH = 65536;
  if (CH < 2048)  CH = 2048;
  unsigned short* bufA = (unsigned short*)carve((size_t)CH*256*2);
  unsigned short* bufB = (unsigned short*)carve((size_t)CH*256*2);
  float* pKV           = (float*)carve((size_t)((CH+511)/512)*65536*4);
  float* pS            = (float*)carve((size_t)(CH/64)*256*4);

  // ---- pre-pass: converts + weight builds + counts
  cvt_b<<<2048,256,0,stream>>>(h_nodes, h_nb, (long)Mn*256);
  cvt_b<<<1024,256,0,stream>>>(s_u, s_ub, (long)Nn*256);
  wp_build<<<dim3(16,4),128,0,stream>>>(Wk, 256,256, WkP, 8, 0);
  wp_build<<<dim3(16,4),128,0,stream>>>(Wv, 256,256, WvP, 8, 0);
  wp_build<<<dim3(16,4),128,0,stream>>>(Wq, 256,256, WqP, 8, 0);
  wp_build<<<dim3(32,8),128,0,stream>>>(mw1, 512,512, m1P, 16, 0);
  wp_build<<<dim3(16,8),128,0,stream>>>(mw2, 512,256, m2P, 16, 0);
  wp_build<<<dim3(16,4),128,0,stream>>>(W4, 256,256, W4P, 8, 0);
  wp_build<<<dim3(16,4),128,0,stream>>>(W2, 256,256, W2P, 8, 0);
  hipMemsetAsync(cntg, 0, (size_t)Mn*4, stream);
  hipMemsetAsync(cnts, 0, (size_t)Nn*4, stream);
  hipMemsetAsync(cntss,0, (size_t)Nn*4, stream);
  count_idx<<<512,256,0,stream>>>(g_dst, En, cntg);
  count_idx<<<512,256,0,stream>>>(s_dst, ESn, cnts);
  count_idx<<<512,256,0,stream>>>(s_src, ESn, cntss);

  Ctx c;
  c.WkP=WkP; c.WvP=WvP; c.WqP=WqP; c.m1P=m1P; c.m2P=m2P;
  c.KVWP=KVWP; c.Wm=Wm; c.KVW=KVW;
  c.bm=bm; c.l1g=l1g; c.l1b=l1b; c.mb1=mb1; c.mb2=mb2; c.l2g=l2g; c.l2b=l2b;
  c.bufA=bufA; c.bufB=bufB;
  c.pKV=pKV; c.pS=pS; c.KV=KV;
  c.CH=CH; c.st=stream;

  // ---- 1. x = enc(h_nodes[:N], s_u) -> h_nb[0:N) (bf16, in place)
  phaseA(c, Nn, s_ub, nullptr);
  phaseB<0>(c, Nn, h_nb, h_nb, nullptr);

  // ---- 2. per-node edge encoder over ALL Mn nodes (KV weighted by g_dst counts),
  //         fused EW4 = enc_out @ W4
  phaseA(c, Mn, h_nb, cntg);
  phaseB<2>(c, Mn, h_nb, EW4, W4P);
  // per-edge: lr_e = conv@W2 + EW4[g_src] + b4 + b2 (conv from f32 h_nodes, occ 3)
  //           + fused BN partials
  {
    const int gbE = (En+63)/64;  // 3125, exact
    edge_final<<<gbE,256,0,stream>>>(h_nodes, g_src, g_dst, conv_w, conv_b,
                                     W2P, EW4, b4, b2, lr_e, bnpart, En);
    bn_mid<<<64,256,0,stream>>>(bnpart, gbE, bnmid);
    bn_finalize<<<1,256,0,stream>>>(bnmid, 64, (long)En, bn_g, bn_b, bnscale, bnshift);
    bn_apply<true><<<2048,256,0,stream>>>(lr_e, (long)En, bnscale, bnshift);
  }

  // ---- 3. per-node social encoder over N nodes (KV weighted by s_dst counts)
  phaseA(c, Nn, h_nb, cnts);
  phaseB<1>(c, Nn, h_nb, nodeS, nullptr);
  // soc = BN(gather(nodeS, s_src)) via count-weighted stats
  bnw_stats<<<64,256,0,stream>>>(nodeS, cntss, Nn, bnmid);
  bn_finalize<<<1,256,0,stream>>>(bnmid, 64, (long)ESn, bn_g, bn_b, bnscale, bnshift);
  bn_apply_gather<<<2048,256,0,stream>>>(nodeS, s_src, (long)ESn, bnscale, bnshift, soc);
}

// Round 23
// 1116.067 us; speedup vs baseline: 1.0478x; 1.0478x over previous
//
#include <hip/hip_runtime.h>

static constexpr int Mn  = 50000;
static constexpr int Nn  = 20000;
static constexpr int En  = 200000;
static constexpr int ESn = 100000;

typedef short short8v __attribute__((ext_vector_type(8)));
typedef short short4v __attribute__((ext_vector_type(4)));
typedef float f32x4   __attribute__((ext_vector_type(4)));

__device__ __forceinline__ float b2f(unsigned short h) {
  unsigned int u = ((unsigned int)h) << 16;
  return __builtin_bit_cast(float, u);
}
__device__ __forceinline__ unsigned short f2b(float f) {
  unsigned int u = __builtin_bit_cast(unsigned int, f);
  u = (u + 0x7FFFu + ((u >> 16) & 1u)) >> 16;
  return (unsigned short)u;
}
__device__ __forceinline__ void gld16(const void* g, void* l) {
  __builtin_amdgcn_global_load_lds(
      (const __attribute__((address_space(1))) void*)g,
      (__attribute__((address_space(3))) void*)l, 16, 0, 0);
}

// ---------------------------------------------------------------- fp32 -> bf16 flat convert
__global__ __launch_bounds__(256) void cvt_b(const float* __restrict__ s,
                                             unsigned short* __restrict__ d, long n) {
  long g  = (long)blockIdx.x*256 + threadIdx.x;
  long st = (long)gridDim.x*256;
  for (; g*8 < n; g += st) {
    const float4 a = *(const float4*)(s + g*8);
    const float4 b = *(const float4*)(s + g*8 + 4);
    short8v o;
    o[0]=(short)f2b(a.x); o[1]=(short)f2b(a.y); o[2]=(short)f2b(a.z); o[3]=(short)f2b(a.w);
    o[4]=(short)f2b(b.x); o[5]=(short)f2b(b.y); o[6]=(short)f2b(b.z); o[7]=(short)f2b(b.w);
    *(short8v*)(d + g*8) = o;
  }
}

// ---------------------------------------------------------------- W [K][N] fp32 -> packed MFMA-fragment order
__global__ __launch_bounds__(128) void wp_build(const float* __restrict__ W, int K, int N,
    unsigned short* __restrict__ WP, int KKd, int kg0) {
  const int t = threadIdx.x;
  const int kk2 = t >> 6, l = t & 63;
  const int c16 = blockIdx.x, ky = blockIdx.y;
  const int k0 = ky*64 + kk2*32 + (l>>4)*8;
  const int n  = c16*16 + (l&15);
  short8v o;
#pragma unroll
  for (int e=0;e<8;++e) o[e] = (short)f2b(W[(long)(k0+e)*N + n]);
  *(short8v*)(WP + (((long)c16*KKd + kg0 + ky*2+kk2)*64 + l)*8) = o;
}

// ---------------------------------------------------------------- KVW[a][c] = sum_b KV[a][b]*Wm[b][c]
__global__ __launch_bounds__(256) void kvw_mul(const float* __restrict__ KV,
    const float* __restrict__ Wm, float* __restrict__ KVW) {
  const int a = blockIdx.x;
  const int c = threadIdx.x;
  float s = 0.f;
  for (int b = 0; b < 256; ++b) s += KV[a*256 + b] * Wm[(long)b*256 + c];
  KVW[a*256 + c] = s;
}

// ---------------------------------------------------------------- index counting (deterministic int atomics)
__global__ __launch_bounds__(256) void count_idx(const int* __restrict__ idx, int n,
                                                 int* __restrict__ cnt) {
  int i = blockIdx.x*256 + threadIdx.x;
  const int st = gridDim.x*256;
  for (; i < n; i += st) atomicAdd(&cnt[idx[i]], 1);
}

// ---------------------------------------------------------------- fused K/V projection -> TRANSPOSED outputs
__global__ __launch_bounds__(256,3) void gemm_kv(
    const unsigned short* __restrict__ X, int aoff,
    const unsigned short* __restrict__ WkP, const unsigned short* __restrict__ WvP,
    unsigned short* __restrict__ KbT, unsigned short* __restrict__ VbT,
    float* __restrict__ pS, int ldp, int nrows, const int* __restrict__ cntw)
{
  __shared__ short xb[4][64*64];
  const int t = threadIdx.x;
  const int w = t >> 6, l = t & 63, q = l >> 4, hw = l & 15;
  const int r0 = blockIdx.x << 6;

  {
    const int sr = l >> 3, sc = l & 7;
    const int gcol = ((sc ^ sr) << 3);
#pragma unroll
    for (int j=0;j<2;++j) {
      int lr = r0 + j*32 + w*8 + sr;
      int lrc = lr < nrows ? lr : nrows-1;
      const unsigned short* src = X + (long)(aoff+lrc)*256 + gcol;
#pragma unroll
      for (int ks=0;ks<4;++ks)
        gld16(src + ks*64, &xb[ks][(j*32 + w*8)*64]);
    }
  }
  asm volatile("s_waitcnt vmcnt(0)" ::: "memory");
  __builtin_amdgcn_s_barrier();

#pragma unroll
  for (int pass=0; pass<2; ++pass) {
    const unsigned short* WP = pass ? WvP : WkP;
    unsigned short* O = pass ? VbT : KbT;
    f32x4 acc[4][4];
#pragma unroll
    for (int m=0;m<4;++m)
#pragma unroll
      for (int n=0;n<4;++n) acc[m][n] = (f32x4){0.f,0.f,0.f,0.f};
    short8v bfc[4], bfn[4];
#pragma unroll
    for (int n=0;n<4;++n)
      bfc[n] = *(const short8v*)(WP + (((long)(w*4+n)*8)*64 + l)*8);
#pragma unroll
    for (int st=0; st<8; ++st) {
      if (st < 7) {
#pragma unroll
        for (int n=0;n<4;++n)
          bfn[n] = *(const short8v*)(WP + (((long)(w*4+n)*8 + st+1)*64 + l)*8);
      }
      const int ks = st >> 1;
      const int kc = ((st&1)<<2) + q;
      short8v af[4];
#pragma unroll
      for (int m=0;m<4;++m)
        af[m] = *(const short8v*)&xb[ks][(m*16+hw)*64 + ((kc^(hw&7))<<3)];
      __builtin_amdgcn_s_setprio(1);
#pragma unroll
      for (int m=0;m<4;++m)
#pragma unroll
        for (int n=0;n<4;++n)
          acc[m][n] = __builtin_amdgcn_mfma_f32_16x16x32_bf16(af[m], bfc[n], acc[m][n], 0,0,0);
      __builtin_amdgcn_s_setprio(0);
#pragma unroll
      for (int n=0;n<4;++n) bfc[n] = bfn[n];
    }
    float colsum[4] = {0.f,0.f,0.f,0.f};
#pragma unroll
    for (int m=0;m<4;++m)
#pragma unroll
      for (int n=0;n<4;++n) {
        const int c = w*64 + n*16 + hw;
        short4v o4;
#pragma unroll
        for (int i=0;i<4;++i) {
          const int lr = r0 + m*16 + q*4 + i;
          float v = 0.f;
          if (lr < nrows) {
            v = acc[m][n][i];
            if (pass == 0) {
              v = v > 0.f ? v + 1.f : __expf(v);
              if (cntw) v *= (float)cntw[aoff + lr];
            }
          }
          if (pass == 0) colsum[n] += v;
          o4[i] = (short)f2b(v);
        }
        *(short4v*)(O + (long)c*ldp + r0 + m*16 + q*4) = o4;
      }
    if (pass == 0) {
#pragma unroll
      for (int n=0;n<4;++n) {
        float s = colsum[n];
        s += __shfl_xor(s, 16);
        s += __shfl_xor(s, 32);
        if (q == 0) pS[(long)blockIdx.x*256 + w*64 + n*16 + hw] = s;
      }
    }
  }
}

// Ks[c] += sum_b pS[b][c]  (one block per column)
__global__ __launch_bounds__(256) void ksum_red(const float* __restrict__ pS, int nb,
    float* __restrict__ Ks) {
  __shared__ float ws[4];
  const int c = blockIdx.x;
  const int t = threadIdx.x;
  float s = 0.f;
  for (int b = t; b < nb; b += 256) s += pS[(long)b*256 + c];
#pragma unroll
  for (int off=32; off; off>>=1) s += __shfl_xor(s, off);
  if ((t & 63) == 0) ws[t >> 6] = s;
  __syncthreads();
  if (t == 0) Ks[c] += ws[0] + ws[1] + ws[2] + ws[3];
}

// ---------------------------------------------------------------- K^T V via MFMA, LDS-free streaming
__global__ __launch_bounds__(256,4) void ktv_mfma(
    const unsigned short* __restrict__ KbT, const unsigned short* __restrict__ VbT,
    int ldp, int rpp, float* __restrict__ pKV)
{
  const int t  = threadIdx.x;
  const int w  = t >> 6;
  const int l  = t & 63;
  const int q  = l >> 4;
  const int hw = l & 15;
  const int wa = w >> 1, wb = w & 1;
  const int a0 = blockIdx.x << 7;
  const int b0 = blockIdx.y << 7;
  const int rbeg = blockIdx.z * rpp;
  const int rend = min(ldp, rbeg + rpp);

  f32x4 acc[4][4];
#pragma unroll
  for (int m=0;m<4;++m)
#pragma unroll
    for (int n=0;n<4;++n) acc[m][n] = (f32x4){0.f,0.f,0.f,0.f};

  const unsigned short* ap[4];
  const unsigned short* bp[4];
#pragma unroll
  for (int m=0;m<4;++m) ap[m] = KbT + (long)(a0 + wa*64 + m*16 + hw)*ldp + q*8;
#pragma unroll
  for (int n=0;n<4;++n) bp[n] = VbT + (long)(b0 + wb*64 + n*16 + hw)*ldp + q*8;

#pragma unroll 4
  for (int r = rbeg; r < rend; r += 32) {
    short8v af[4], bf[4];
#pragma unroll
    for (int m=0;m<4;++m) af[m] = *(const short8v*)(ap[m] + r);
#pragma unroll
    for (int n=0;n<4;++n) bf[n] = *(const short8v*)(bp[n] + r);
#pragma unroll
    for (int m=0;m<4;++m)
#pragma unroll
      for (int n=0;n<4;++n)
        acc[m][n] = __builtin_amdgcn_mfma_f32_16x16x32_bf16(af[m], bf[n], acc[m][n], 0,0,0);
  }

  const long base = (long)blockIdx.z * 65536;
#pragma unroll
  for (int m=0;m<4;++m)
#pragma unroll
    for (int i=0;i<4;++i) {
      const int a = a0 + wa*64 + m*16 + q*4 + i;
#pragma unroll
      for (int n=0;n<4;++n) {
        const int b = b0 + wb*64 + n*16 + hw;
        pKV[base + (long)a*256 + b] = acc[m][n][i];
      }
    }
}

__global__ __launch_bounds__(256) void kv_accum(const float* __restrict__ pKV, int P,
                                                float* __restrict__ KV) {
  const int i = blockIdx.x*256 + threadIdx.x;
  float s = 0.f;
  for (int p=0;p<P;++p) s += pKV[(long)p*65536 + i];
  KV[i] += s;
}

// ---------------------------------------------------------------- fused encoder phase B, 64 rows/block (r13/r21 form)
// OMODE: 0 = bf16 out; 1 = f32 out; 2 = bf16 kept in LDS + EW4 = out@W4 (f32) tail
template<int OMODE>
__global__ __launch_bounds__(256,2) void encB(
    const unsigned short* __restrict__ X, int aoff,
    const unsigned short* __restrict__ WqP, const unsigned short* __restrict__ KVWP,
    const unsigned short* __restrict__ m1P, const unsigned short* __restrict__ m2P,
    const float* __restrict__ Ksum, const float* __restrict__ bmv,
    const float* __restrict__ l1g, const float* __restrict__ l1b,
    const float* __restrict__ mb1, const float* __restrict__ mb2,
    const float* __restrict__ l2g, const float* __restrict__ l2b,
    const unsigned short* __restrict__ WfP,
    void* outv, int dc0, int nrows)
{
  __shared__ short xb[4][64*64];
  __shared__ short qb[4][64*64];
  __shared__ short y1b[64*64];
  __shared__ float2 red[64][4];
  __shared__ float Zl[64];

  const int t = threadIdx.x;
  const int w = t >> 6, l = t & 63, q = l >> 4, hw = l & 15;
  const int wc = w;
  const int r0 = blockIdx.x << 6;
  const int sr = l >> 3, sc = l & 7;
  const int gcol = ((sc ^ sr) << 3);

  {
#pragma unroll
    for (int j=0;j<2;++j) {
      int lr = r0 + j*32 + w*8 + sr;
      int lrc = lr < nrows ? lr : nrows-1;
      const unsigned short* src = X + (long)(aoff+lrc)*256 + gcol;
#pragma unroll
      for (int ks=0;ks<4;++ks)
        gld16(src + ks*64, &xb[ks][(j*32 + w*8)*64]);
    }
  }
  asm volatile("s_waitcnt vmcnt(0)" ::: "memory");
  __builtin_amdgcn_s_barrier();

  f32x4 acc[4][4];

  auto GEMM256 = [&](const short* Asrc, const unsigned short* WP) {
#pragma unroll
    for (int m=0;m<4;++m)
#pragma unroll
      for (int n=0;n<4;++n) acc[m][n] = (f32x4){0.f,0.f,0.f,0.f};
    short8v bfc[4], bfn[4];
#pragma unroll
    for (int n=0;n<4;++n)
      bfc[n] = *(const short8v*)(WP + (((long)(wc*4+n)*8)*64 + l)*8);
#pragma unroll
    for (int st=0; st<8; ++st) {
      if (st < 7) {
#pragma unroll
        for (int n=0;n<4;++n)
          bfn[n] = *(const short8v*)(WP + (((long)(wc*4+n)*8 + st+1)*64 + l)*8);
      }
      const int ks = st >> 1;
      const int kc = ((st&1)<<2) + q;
      short8v af[4];
#pragma unroll
      for (int m=0;m<4;++m)
        af[m] = *(const short8v*)&Asrc[ks*4096 + (m*16+hw)*64 + ((kc^(hw&7))<<3)];
      __builtin_amdgcn_s_setprio(1);
#pragma unroll
      for (int m=0;m<4;++m)
#pragma unroll
        for (int n=0;n<4;++n)
          acc[m][n] = __builtin_amdgcn_mfma_f32_16x16x32_bf16(af[m], bfc[n], acc[m][n], 0,0,0);
      __builtin_amdgcn_s_setprio(0);
#pragma unroll
      for (int n=0;n<4;++n) bfc[n] = bfn[n];
    }
  };

  // G1: Q = elu1(x @ Wq), Z partials
  GEMM256(&xb[0][0], WqP);
  {
    float ksv[4];
#pragma unroll
    for (int n=0;n<4;++n) ksv[n] = Ksum[wc*64+n*16+hw];
#pragma unroll
    for (int m=0;m<4;++m)
#pragma unroll
      for (int n=0;n<4;++n)
#pragma unroll
        for (int i=0;i<4;++i) {
          float v = acc[m][n][i];
          acc[m][n][i] = v > 0.f ? v + 1.f : __expf(v);
        }
#pragma unroll
    for (int m=0;m<4;++m)
#pragma unroll
      for (int i=0;i<4;++i) {
        float z = 0.f;
#pragma unroll
        for (int n=0;n<4;++n) z += acc[m][n][i]*ksv[n];
#pragma unroll
        for (int off=1; off<16; off<<=1) z += __shfl_xor(z, off);
        if (hw==0) red[m*16+q*4+i][wc] = make_float2(z, 0.f);
      }
#pragma unroll
    for (int m=0;m<4;++m)
#pragma unroll
      for (int i=0;i<4;++i) {
        const int row = m*16+q*4+i;
        const int sw = row & 7;
#pragma unroll
        for (int n=0;n<4;++n)
          qb[wc][row*64 + (((n*2+(hw>>3)) ^ sw)<<3) + (hw&7)] = (short)f2b(acc[m][n][i]);
      }
  }
  __syncthreads();
  if (wc==0 && hw==0) {
#pragma unroll
    for (int m=0;m<4;++m)
#pragma unroll
      for (int i=0;i<4;++i) {
        const int row = m*16+q*4+i;
        Zl[row] = red[row][0].x + red[row][1].x + red[row][2].x + red[row][3].x + 1e-6f;
      }
  }

  // G2': msg = LN((Q @ KVW)/Z + bm)
  GEMM256(&qb[0][0], KVWP);
  __syncthreads();
#pragma unroll
  for (int m=0;m<4;++m) {
    const f32x4 z = *(const f32x4*)&Zl[m*16+q*4];
#pragma unroll
    for (int i=0;i<4;++i) {
      const float iz = 1.f / z[i];
#pragma unroll
      for (int n=0;n<4;++n) acc[m][n][i] *= iz;
    }
  }
  {
    float lg[4], lb[4];
#pragma unroll
    for (int n=0;n<4;++n) {
      const int c = wc*64+n*16+hw;
      const float bv = bmv[c];
      lg[n] = l1g[c]; lb[n] = l1b[c];
#pragma unroll
      for (int m=0;m<4;++m)
#pragma unroll
        for (int i=0;i<4;++i) acc[m][n][i] += bv;
    }
    float s1[4][4], s2[4][4];
#pragma unroll
    for (int m=0;m<4;++m)
#pragma unroll
      for (int i=0;i<4;++i) {
        float s=0.f, sq=0.f;
#pragma unroll
        for (int n=0;n<4;++n){ const float v=acc[m][n][i]; s+=v; sq+=v*v; }
        s1[m][i]=s; s2[m][i]=sq;
      }
#pragma unroll
    for (int off=1; off<16; off<<=1)
#pragma unroll
      for (int m=0;m<4;++m)
#pragma unroll
        for (int i=0;i<4;++i) {
          s1[m][i] += __shfl_xor(s1[m][i], off);
          s2[m][i] += __shfl_xor(s2[m][i], off);
        }
    if (hw==0) {
#pragma unroll
      for (int m=0;m<4;++m)
#pragma unroll
        for (int i=0;i<4;++i)
          red[m*16+q*4+i][wc] = make_float2(s1[m][i], s2[m][i]);
    }
    __syncthreads();
#pragma unroll
    for (int m=0;m<4;++m)
#pragma unroll
      for (int i=0;i<4;++i) {
        const int row = m*16+q*4+i;
        float ts=0.f, tq=0.f;
#pragma unroll
        for (int ww=0;ww<4;++ww){ const float2 v=red[row][ww]; ts+=v.x; tq+=v.y; }
        const float mmu = ts*(1.f/256.f);
        float var = tq*(1.f/256.f) - mmu*mmu;
        var = var>0.f ? var : 0.f;
        const float rs = rsqrtf(var + 1e-5f);
        const int sw = row & 7;
#pragma unroll
        for (int n=0;n<4;++n) {
          const float v = (acc[m][n][i]-mmu)*rs*lg[n] + lb[n];
          qb[wc][row*64 + (((n*2+(hw>>3)) ^ sw)<<3) + (hw&7)] = (short)f2b(v);
        }
      }
  }
  __syncthreads();

  // MLP
  f32x4 oacc[4][4];
#pragma unroll
  for (int m=0;m<4;++m)
#pragma unroll
    for (int n=0;n<4;++n) oacc[m][n] = (f32x4){0.f,0.f,0.f,0.f};

  for (int ct=0; ct<8; ++ct) {
    f32x4 ya[4];
#pragma unroll
    for (int m=0;m<4;++m) ya[m] = (f32x4){0.f,0.f,0.f,0.f};
    {
      short8v b0c, b0n;
      b0c = *(const short8v*)(m1P + (((long)(ct*4+wc)*16)*64 + l)*8);
#pragma unroll
      for (int st=0; st<16; ++st) {
        if (st < 15)
          b0n = *(const short8v*)(m1P + (((long)(ct*4+wc)*16 + st+1)*64 + l)*8);
        const int ks = st >> 1;
        const int kc = ((st&1)<<2) + q;
        const short* As_ = (ks<4) ? &xb[ks][0] : &qb[ks-4][0];
        __builtin_amdgcn_s_setprio(1);
#pragma unroll
        for (int m=0;m<4;++m) {
          const short8v af = *(const short8v*)&As_[(m*16+hw)*64 + ((kc^(hw&7))<<3)];
          ya[m] = __builtin_amdgcn_mfma_f32_16x16x32_bf16(af, b0c, ya[m], 0,0,0);
        }
        __builtin_amdgcn_s_setprio(0);
        b0c = b0n;
      }
    }
    const float b1 = mb1[ct*64 + wc*16 + hw];
#pragma unroll
    for (int m=0;m<4;++m)
#pragma unroll
      for (int i=0;i<4;++i) {
        const int row = m*16+q*4+i;
        float v = ya[m][i] + b1; v = v>0.f ? v : 0.f;
        y1b[row*64 + (((wc*2+(hw>>3)) ^ (row&7))<<3) + (hw&7)] = (short)f2b(v);
      }
    __syncthreads();
    {
      short8v bfc[4], bfn[4];
#pragma unroll
      for (int n=0;n<4;++n)
        bfc[n] = *(const short8v*)(m2P + (((long)(wc*4+n)*16 + ct*2)*64 + l)*8);
#pragma unroll
      for (int kk=0;kk<2;++kk) {
        if (kk == 0) {
#pragma unroll
          for (int n=0;n<4;++n)
            bfn[n] = *(const short8v*)(m2P + (((long)(wc*4+n)*16 + ct*2+1)*64 + l)*8);
        }
        const int kc = (kk<<2)+q;
        short8v af[4];
#pragma unroll
        for (int m=0;m<4;++m)
          af[m] = *(const short8v*)&y1b[(m*16+hw)*64 + ((kc^(hw&7))<<3)];
        __builtin_amdgcn_s_setprio(1);
#pragma unroll
        for (int m=0;m<4;++m)
#pragma unroll
          for (int n=0;n<4;++n)
            oacc[m][n] = __builtin_amdgcn_mfma_f32_16x16x32_bf16(af[m], bfc[n], oacc[m][n], 0,0,0);
        __builtin_amdgcn_s_setprio(0);
#pragma unroll
        for (int n=0;n<4;++n) bfc[n] = bfn[n];
      }
    }
    __syncthreads();
  }

  // final: out = x + LN(oacc + mb2)
  {
    float lg[4], lb[4];
#pragma unroll
    for (int n=0;n<4;++n) {
      const int c = wc*64+n*16+hw;
      const float bv = mb2[c];
      lg[n] = l2g[c]; lb[n] = l2b[c];
#pragma unroll
      for (int m=0;m<4;++m)
#pragma unroll
        for (int i=0;i<4;++i) oacc[m][n][i] += bv;
    }
    float s1[4][4], s2[4][4];
#pragma unroll
    for (int m=0;m<4;++m)
#pragma unroll
      for (int i=0;i<4;++i) {
        float s=0.f, sq=0.f;
#pragma unroll
        for (int n=0;n<4;++n){ const float v=oacc[m][n][i]; s+=v; sq+=v*v; }
        s1[m][i]=s; s2[m][i]=sq;
      }
#pragma unroll
    for (int off=1; off<16; off<<=1)
#pragma unroll
      for (int m=0;m<4;++m)
#pragma unroll
        for (int i=0;i<4;++i) {
          s1[m][i] += __shfl_xor(s1[m][i], off);
          s2[m][i] += __shfl_xor(s2[m][i], off);
        }
    if (hw==0) {
#pragma unroll
      for (int m=0;m<4;++m)
#pragma unroll
        for (int i=0;i<4;++i)
          red[m*16+q*4+i][wc] = make_float2(s1[m][i], s2[m][i]);
    }
    __syncthreads();
#pragma unroll
    for (int m=0;m<4;++m)
#pragma unroll
      for (int i=0;i<4;++i) {
        const int row = m*16+q*4+i;
        const int lr = r0 + row;
        if (lr >= nrows) continue;
        float ts=0.f, tq=0.f;
#pragma unroll
        for (int ww=0;ww<4;++ww){ const float2 v=red[row][ww]; ts+=v.x; tq+=v.y; }
        const float mmu = ts*(1.f/256.f);
        float var = tq*(1.f/256.f) - mmu*mmu;
        var = var>0.f ? var : 0.f;
        const float rs = rsqrtf(var + 1e-5f);
        const int sw = row & 7;
#pragma unroll
        for (int n=0;n<4;++n) {
          const int c = wc*64+n*16+hw;
          float v = (oacc[m][n][i]-mmu)*rs*lg[n] + lb[n];
          v += b2f((unsigned short)xb[wc][row*64 + (((n*2+(hw>>3)) ^ sw)<<3) + (hw&7)]);
          if constexpr (OMODE == 2) {
            qb[wc][row*64 + (((n*2+(hw>>3)) ^ sw)<<3) + (hw&7)] = (short)f2b(v);
          } else {
            const long off2 = (long)(dc0+lr)*256 + c;
            if constexpr (OMODE == 1) ((float*)outv)[off2] = v;
            else ((unsigned short*)outv)[off2] = f2b(v);
          }
        }
      }
  }

  // fused tail (OMODE==2): EW4 = out @ W4 (f32)
  if constexpr (OMODE == 2) {
    __syncthreads();
    GEMM256(&qb[0][0], WfP);
#pragma unroll
    for (int m=0;m<4;++m)
#pragma unroll
      for (int i=0;i<4;++i) {
        const int lr = r0 + m*16 + q*4 + i;
        if (lr >= nrows) continue;
#pragma unroll
        for (int n=0;n<4;++n)
          ((float*)outv)[(long)(dc0+lr)*256 + wc*64+n*16+hw] = acc[m][n][i];
      }
  }
}

// ---------------------------------------------------------------- fused conv + W2 + EW4 gather + BN partials
// r21 form (occ 3, f32 conv reads) + fused per-block BN sum/sumsq partials.
// lr_e stores are NON-TEMPORAL: write-once streaming, frees L2 for the EW4 gather.
__global__ __launch_bounds__(256,3) void edge_final(
    const float* __restrict__ h, const int* __restrict__ gs, const int* __restrict__ gd,
    const float* __restrict__ cw, const float* __restrict__ cb,
    const unsigned short* __restrict__ W2P, const float* __restrict__ EW4,
    const float* __restrict__ b4, const float* __restrict__ b2,
    float* __restrict__ lr_e, float* __restrict__ pstat, int nrows)
{
  __shared__ short xb[4][64*64];
  const int t = threadIdx.x;
  const int w = t >> 6, l = t & 63, q = l >> 4, hw = l & 15;
  const int r0 = blockIdx.x << 6;

  const float c0=cw[0],c1=cw[1],c2=cw[2],c3=cw[3],c4=cw[4],c5=cw[5],cbb=cb[0];
  for (int it=0; it<16; ++it) {
    const int row = w*16 + it;
    const int lr = r0 + row;
    const int lrc = lr < nrows ? lr : nrows-1;
    const float4 s = *(const float4*)(h + (long)gs[lrc]*256 + l*4);
    const float4 d = *(const float4*)(h + (long)gd[lrc]*256 + l*4);
    float smw = __shfl_up(s.w, 1); if (l==0) smw = 0.f;
    float spx = __shfl_down(s.x, 1); if (l==63) spx = 0.f;
    float dmw = __shfl_up(d.w, 1); if (l==0) dmw = 0.f;
    float dpx = __shfl_down(d.x, 1); if (l==63) dpx = 0.f;
    short4v o;
    o[0]=(short)f2b(cbb + c0*smw + c1*s.x + c2*s.y + c3*dmw + c4*d.x + c5*d.y);
    o[1]=(short)f2b(cbb + c0*s.x + c1*s.y + c2*s.z + c3*d.x + c4*d.y + c5*d.z);
    o[2]=(short)f2b(cbb + c0*s.y + c1*s.z + c2*s.w + c3*d.y + c4*d.z + c5*d.w);
    o[3]=(short)f2b(cbb + c0*s.z + c1*s.w + c2*spx + c3*d.z + c4*d.w + c5*dpx);
    const int ks = l >> 4;
    const int g  = (l & 15) >> 1;
    *(short4v*)&xb[ks][row*64 + ((g ^ (row&7))<<3) + (l&1)*4] = o;
  }
  __syncthreads();

  f32x4 acc[4][4];
#pragma unroll
  for (int m=0;m<4;++m)
#pragma unroll
    for (int n=0;n<4;++n) acc[m][n] = (f32x4){0.f,0.f,0.f,0.f};
  short8v bfc[4], bfn[4];
#pragma unroll
  for (int n=0;n<4;++n)
    bfc[n] = *(const short8v*)(W2P + (((long)(w*4+n)*8)*64 + l)*8);
#pragma unroll
  for (int st=0; st<8; ++st) {
    if (st < 7) {
#pragma unroll
      for (int n=0;n<4;++n)
        bfn[n] = *(const short8v*)(W2P + (((long)(w*4+n)*8 + st+1)*64 + l)*8);
    }
    const int ks = st >> 1;
    const int kc = ((st&1)<<2) + q;
    short8v af[4];
#pragma unroll
    for (int m=0;m<4;++m)
      af[m] = *(const short8v*)&xb[ks][(m*16+hw)*64 + ((kc^(hw&7))<<3)];
    __builtin_amdgcn_s_setprio(1);
#pragma unroll
    for (int m=0;m<4;++m)
#pragma unroll
      for (int n=0;n<4;++n)
        acc[m][n] = __builtin_amdgcn_mfma_f32_16x16x32_bf16(af[m], bfc[n], acc[m][n], 0,0,0);
    __builtin_amdgcn_s_setprio(0);
#pragma unroll
    for (int n=0;n<4;++n) bfc[n] = bfn[n];
  }
  float bia[4];
#pragma unroll
  for (int n=0;n<4;++n) {
    const int c = w*64+n*16+hw;
    bia[n] = b4[c] + b2[c];
  }
  float cs[4] = {0.f,0.f,0.f,0.f};
  float cq2[4] = {0.f,0.f,0.f,0.f};
#pragma unroll
  for (int m=0;m<4;++m)
#pragma unroll
    for (int i=0;i<4;++i) {
      const int lr = r0 + m*16 + q*4 + i;
      if (lr >= nrows) continue;
      const long rid = (long)gs[lr];
#pragma unroll
      for (int n=0;n<4;++n) {
        const int c = w*64+n*16+hw;
        const float v = acc[m][n][i] + EW4[rid*256 + c] + bia[n];
        cs[n] += v; cq2[n] += v*v;
        __builtin_nontemporal_store(v, &lr_e[(long)lr*256 + c]);
      }
    }
#pragma unroll
  for (int n=0;n<4;++n) {
    float a = cs[n];
    a += __shfl_xor(a, 16);
    a += __shfl_xor(a, 32);
    float b = cq2[n];
    b += __shfl_xor(b, 16);
    b += __shfl_xor(b, 32);
    if (q == 0) {
      const int c = w*64+n*16+hw;
      pstat[(long)blockIdx.x*512 + c] = a;
      pstat[(long)blockIdx.x*512 + 256 + c] = b;
    }
  }
}

// ---------------------------------------------------------------- BN apply (in place, f32)
template<bool R>
__global__ __launch_bounds__(256) void bn_apply(float* __restrict__ X, long rows,
    const float* __restrict__ sc, const float* __restrict__ sh) {
  const long n4 = rows*64;
  long i = (long)blockIdx.x*256 + threadIdx.x;
  const long st = (long)gridDim.x*256;
  for (; i<n4; i+=st) {
    const int cq = (int)(i & 63);
    float4 v = ((float4*)X)[i];
    const float4 s4 = ((const float4*)sc)[cq];
    const float4 h4 = ((const float4*)sh)[cq];
    v.x = v.x*s4.x + h4.x; v.y = v.y*s4.y + h4.y;
    v.z = v.z*s4.z + h4.z; v.w = v.w*s4.w + h4.w;
    if (R) { v.x=fmaxf(v.x,0.f); v.y=fmaxf(v.y,0.f); v.z=fmaxf(v.z,0.f); v.w=fmaxf(v.w,0.f); }
    ((float4*)X)[i] = v;
  }
}

// count-weighted node stats: part[b][512] over 64 blocks
__global__ __launch_bounds__(256) void bnw_stats(const float* __restrict__ X,
    const int* __restrict__ cnt, int rows, float* __restrict__ part) {
  const int b = blockIdx.x, c = threadIdx.x;
  float s=0.f, s2=0.f;
  for (int r=b; r<rows; r+=64) {
    const float wgt = (float)cnt[r];
    if (wgt != 0.f) {
      const float v = X[(long)r*256 + c];
      s += wgt*v; s2 += wgt*v*v;
    }
  }
  part[(long)b*512 + c] = s;
  part[(long)b*512 + 256 + c] = s2;
}

__global__ __launch_bounds__(256) void bn_mid(const float* __restrict__ part, int PE,
    float* __restrict__ mid) {
  const int g = blockIdx.x, c = threadIdx.x;
  float s=0.f, s2=0.f;
  for (int p=g; p<PE; p+=64) {
    s  += part[(long)p*512 + c];
    s2 += part[(long)p*512 + 256 + c];
  }
  mid[(long)g*512 + c] = s;
  mid[(long)g*512 + 256 + c] = s2;
}

__global__ __launch_bounds__(256) void bn_finalize(const float* __restrict__ part, int P,
    long rows, const float* __restrict__ g, const float* __restrict__ b,
    float* __restrict__ scale, float* __restrict__ shift) {
  const int c = threadIdx.x;
  float s=0.f, s2=0.f;
  for (int p=0;p<P;++p) { s += part[(long)p*512 + c]; s2 += part[(long)p*512 + 256 + c]; }
  const float inv = 1.f/(float)rows;
  const float mu = s*inv;
  float var = s2*inv - mu*mu;
  var = var > 0.f ? var : 0.f;
  const float rs = rsqrtf(var + 1e-5f);
  scale[c] = g[c]*rs;
  shift[c] = b[c] - mu*g[c]*rs;
}

// soc[e] = nodeS[s_src[e]]*scale + shift
__global__ __launch_bounds__(256) void bn_apply_gather(const float* __restrict__ nodeS,
    const int* __restrict__ sidx, long rows,
    const float* __restrict__ sc, const float* __restrict__ sh,
    float* __restrict__ out) {
  const long n4 = rows*64;
  long i = (long)blockIdx.x*256 + threadIdx.x;
  const long st = (long)gridDim.x*256;
  for (; i<n4; i+=st) {
    const long row = i >> 6;
    const int cq = (int)(i & 63);
    const long rid = (long)sidx[row];
    float4 v = *(const float4*)(nodeS + rid*256 + cq*4);
    const float4 s4 = ((const float4*)sc)[cq];
    const float4 h4 = ((const float4*)sh)[cq];
    v.x = v.x*s4.x + h4.x; v.y = v.y*s4.y + h4.y;
    v.z = v.z*s4.z + h4.z; v.w = v.w*s4.w + h4.w;
    ((float4*)out)[i] = v;
  }
}

// ---------------------------------------------------------------- host-side
struct Ctx {
  const unsigned short *WkP,*WvP,*WqP,*m1P,*m2P;
  unsigned short* KVWP;
  const float *Wm;
  float* KVW;
  const float *bm,*l1g,*l1b,*mb1,*mb2,*l2g,*l2b;
  unsigned short *bufA,*bufB;
  float *pKV,*pS,*KV;
  long CH;
  hipStream_t st;
};

static void phaseA(const Ctx& c, long S, const unsigned short* Bsrc, const int* cnt) {
  hipMemsetAsync(c.KV, 0, 65792*sizeof(float), c.st);
  for (long s0=0; s0<S; s0+=c.CH) {
    const int n = (int)((S-s0 < c.CH) ? (S-s0) : c.CH);
    const int gb = (n+63)/64;
    const int ldp = gb*64;
    gemm_kv<<<gb,256,0,c.st>>>(Bsrc, (int)s0, c.WkP, c.WvP, c.bufA, c.bufB, c.pS, ldp, n, cnt);
    const int P = (ldp+511)/512;
    ktv_mfma<<<dim3(2,2,P),256,0,c.st>>>(c.bufA, c.bufB, ldp, 512, c.pKV);
    kv_accum<<<256,256,0,c.st>>>(c.pKV, P, c.KV);
    ksum_red<<<256,256,0,c.st>>>(c.pS, gb, c.KV+65536);
  }
  kvw_mul<<<256,256,0,c.st>>>(c.KV, c.Wm, c.KVW);
  wp_build<<<dim3(16,4),128,0,c.st>>>(c.KVW, 256, 256, c.KVWP, 8, 0);
}

template<int OMODE>
static void phaseB(const Ctx& c, long L, const unsigned short* Asrc, void* out,
                   const unsigned short* WfP) {
  const float* Ksum = c.KV + 65536;
  for (long l0=0; l0<L; l0+=c.CH) {
    const int n = (int)((L-l0 < c.CH) ? (L-l0) : c.CH);
    const int gb = (n+63)/64;
    encB<OMODE><<<gb,256,0,c.st>>>(Asrc, (int)l0,
        c.WqP, c.KVWP, c.m1P, c.m2P, Ksum, c.bm, c.l1g, c.l1b,
        c.mb1, c.mb2, c.l2g, c.l2b, WfP, out, (int)l0, n);
  }
}

extern "C" void kernel_launch(void* const* d_in, const int* in_sizes, int n_in,
                              void* d_out, int out_size, void* d_ws, size_t ws_size,
                              hipStream_t stream) {
  const float* h_nodes = (const float*)d_in[0];
  const float* s_u     = (const float*)d_in[1];
  const int*   g_src   = (const int*)d_in[2];
  const int*   g_dst   = (const int*)d_in[3];
  const int*   s_src   = (const int*)d_in[4];
  const int*   s_dst   = (const int*)d_in[5];
  const float* conv_w  = (const float*)d_in[6];
  const float* conv_b  = (const float*)d_in[7];
  const float* W2      = (const float*)d_in[8];
  const float* b2      = (const float*)d_in[9];
  const float* W4      = (const float*)d_in[10];
  const float* b4      = (const float*)d_in[11];
  const float* bn_g    = (const float*)d_in[12];
  const float* bn_b    = (const float*)d_in[13];
  const float* Wq      = (const float*)d_in[14];
  const float* Wk      = (const float*)d_in[15];
  const float* Wv      = (const float*)d_in[16];
  const float* Wm      = (const float*)d_in[17];
  const float* bm      = (const float*)d_in[18];
  const float* l1g     = (const float*)d_in[19];
  const float* l1b     = (const float*)d_in[20];
  const float* mw1     = (const float*)d_in[21];
  const float* mb1     = (const float*)d_in[22];
  const float* mw2     = (const float*)d_in[23];
  const float* mb2     = (const float*)d_in[24];
  const float* l2g     = (const float*)d_in[25];
  const float* l2b     = (const float*)d_in[26];
  (void)in_sizes; (void)n_in; (void)out_size;

  float* lr_e = (float*)d_out;                 // [E,256]
  float* soc  = lr_e + (size_t)En*256;         // [ES,256]

  char* base = (char*)d_ws;
  size_t off = 0;
  auto carve = [&](size_t bytes)->void* {
    void* p = (void*)(base + off);
    off = (off + bytes + 255) & ~(size_t)255;
    return p;
  };
  unsigned short* h_nb = (unsigned short*)carve((size_t)Mn*256*2);
  unsigned short* s_ub = (unsigned short*)carve((size_t)Nn*256*2);
  unsigned short* WkP  = (unsigned short*)carve(65536*2);
  unsigned short* WvP  = (unsigned short*)carve(65536*2);
  unsigned short* WqP  = (unsigned short*)carve(65536*2);
  unsigned short* m1P  = (unsigned short*)carve(262144*2);
  unsigned short* m2P  = (unsigned short*)carve(131072*2);
  unsigned short* W4P  = (unsigned short*)carve(65536*2);
  unsigned short* W2P  = (unsigned short*)carve(65536*2);
  unsigned short* KVWP = (unsigned short*)carve(65536*2);
  float* KV            = (float*)carve(65792*4);
  float* KVW           = (float*)carve(65536*4);
  float* bnpart        = (float*)carve((size_t)3200*512*4);
  float* bnmid         = (float*)carve((size_t)64*512*4);
  float* bnscale       = (float*)carve(256*4);
  float* bnshift       = (float*)carve(256*4);
  float* EW4           = (float*)carve((size_t)Mn*256*4);
  float* nodeS         = (float*)carve((size_t)Nn*256*4);
  int* cntg            = (int*)carve((size_t)Mn*4);
  int* cnts            = (int*)carve((size_t)Nn*4);
  int* cntss           = (int*)carve((size_t)Nn*4);

  const size_t remain = ws_size > off ? ws_size - off : 0;
  // per 1024 rows: bufA+bufB 1 MiB + pKV 512 KiB + pS 16 KiB
  long CH = (long)(remain / 1589248) * 1024;
  if (CH > 65536) CH = 65536;
  if (CH < 2048)  CH = 2048;
  unsigned short* bufA = (unsigned short*)carve((size_t)CH*256*2);
  unsigned short* bufB = (unsigned short*)carve((size_t)CH*256*2);
  float* pKV           = (float*)carve((size_t)((CH+511)/512)*65536*4);
  float* pS            = (float*)carve((size_t)(CH/64)*256*4);

  // ---- pre-pass: converts + weight builds + counts
  cvt_b<<<2048,256,0,stream>>>(h_nodes, h_nb, (long)Mn*256);
  cvt_b<<<1024,256,0,stream>>>(s_u, s_ub, (long)Nn*256);
  wp_build<<<dim3(16,4),128,0,stream>>>(Wk, 256,256, WkP, 8, 0);
  wp_build<<<dim3(16,4),128,0,stream>>>(Wv, 256,256, WvP, 8, 0);
  wp_build<<<dim3(16,4),128,0,stream>>>(Wq, 256,256, WqP, 8, 0);
  wp_build<<<dim3(32,8),128,0,stream>>>(mw1, 512,512, m1P, 16, 0);
  wp_build<<<dim3(16,8),128,0,stream>>>(mw2, 512,256, m2P, 16, 0);
  wp_build<<<dim3(16,4),128,0,stream>>>(W4, 256,256, W4P, 8, 0);
  wp_build<<<dim3(16,4),128,0,stream>>>(W2, 256,256, W2P, 8, 0);
  hipMemsetAsync(cntg, 0, (size_t)Mn*4, stream);
  hipMemsetAsync(cnts, 0, (size_t)Nn*4, stream);
  hipMemsetAsync(cntss,0, (size_t)Nn*4, stream);
  count_idx<<<512,256,0,stream>>>(g_dst, En, cntg);
  count_idx<<<512,256,0,stream>>>(s_dst, ESn, cnts);
  count_idx<<<512,256,0,stream>>>(s_src, ESn, cntss);

  Ctx c;
  c.WkP=WkP; c.WvP=WvP; c.WqP=WqP; c.m1P=m1P; c.m2P=m2P;
  c.KVWP=KVWP; c.Wm=Wm; c.KVW=KVW;
  c.bm=bm; c.l1g=l1g; c.l1b=l1b; c.mb1=mb1; c.mb2=mb2; c.l2g=l2g; c.l2b=l2b;
  c.bufA=bufA; c.bufB=bufB;
  c.pKV=pKV; c.pS=pS; c.KV=KV;
  c.CH=CH; c.st=stream;

  // ---- 1. x = enc(h_nodes[:N], s_u) -> h_nb[0:N) (bf16, in place)
  phaseA(c, Nn, s_ub, nullptr);
  phaseB<0>(c, Nn, h_nb, h_nb, nullptr);

  // ---- 2. per-node edge encoder over ALL Mn nodes (KV weighted by g_dst counts),
  //         fused EW4 = enc_out @ W4
  phaseA(c, Mn, h_nb, cntg);
  phaseB<2>(c, Mn, h_nb, EW4, W4P);
  // per-edge: lr_e = conv@W2 + EW4[g_src] + b4 + b2 (conv from f32 h_nodes, occ 3)
  //           + fused BN partials; lr_e stores non-temporal
  {
    const int gbE = (En+63)/64;  // 3125, exact
    edge_final<<<gbE,256,0,stream>>>(h_nodes, g_src, g_dst, conv_w, conv_b,
                                     W2P, EW4, b4, b2, lr_e, bnpart, En);
    bn_mid<<<64,256,0,stream>>>(bnpart, gbE, bnmid);
    bn_finalize<<<1,256,0,stream>>>(bnmid, 64, (long)En, bn_g, bn_b, bnscale, bnshift);
    bn_apply<true><<<2048,256,0,stream>>>(lr_e, (long)En, bnscale, bnshift);
  }

  // ---- 3. per-node social encoder over N nodes (KV weighted by s_dst counts)
  phaseA(c, Nn, h_nb, cnts);
  phaseB<1>(c, Nn, h_nb, nodeS, nullptr);
  // soc = BN(gather(nodeS, s_src)) via count-weighted stats
  bnw_stats<<<64,256,0,stream>>>(nodeS, cntss, Nn, bnmid);
  bn_finalize<<<1,256,0,stream>>>(bnmid, 64, (long)ESn, bn_g, bn_b, bnscale, bnshift);
  bn_apply_gather<<<2048,256,0,stream>>>(nodeS, s_src, (long)ESn, bnscale, bnshift, soc);
}